// Round 7
// baseline (362.721 us; speedup 1.0000x reference)
//
#include <hip/hip_runtime.h>
#include <stdint.h>

// CosineSimilarityCodebook: X[16384,256] f32, EMB[8192,256] f32 (re-l2norm'd).
// out = [quantized 16384*256 f32][indices 16384 as f32]
// R6 (resubmit after container failure): A-fragments direct from global (L2),
// B-only LDS (32KB dbuf, swizzled), 512-thread blocks (8 waves, 4 waves/SIMD
// target), fused norm+split_e.
// Math identical to R4/R5 (absmax 0.0 x3): dist = hh + (h*lo' + lo'*h)/512.

#define M_ROWS 16384
#define KCODES 8192
#define DDIM   256

#define BR   128
#define BCC  128
#define BK   32
#define NSPLIT 8
#define CPS  (KCODES / NSPLIT)              // 1024
#define NSLICE ((CPS / BCC) * (DDIM / BK))  // 64
#define LSCALE     512.0f
#define INV_LSCALE (1.0f / 512.0f)

typedef _Float16 half4v __attribute__((ext_vector_type(4)));
typedef _Float16 half8v __attribute__((ext_vector_type(8)));
typedef float    f32x4  __attribute__((ext_vector_type(4)));

__device__ __forceinline__ unsigned int fkey(float f) {
    unsigned int u = __float_as_uint(f);
    return (u & 0x80000000u) ? ~u : (u | 0x80000000u);
}

__device__ __forceinline__ void gload16(const void* g, void* l) {
    __builtin_amdgcn_global_load_lds(
        (const __attribute__((address_space(1))) void*)g,
        (__attribute__((address_space(3))) void*)l, 16, 0, 0);
}

// ---------- precompute ----------

// fused: per-row l2 norm + scale + f16 hi/lo split for embeddings (wave per row)
__global__ void norm_split_e_kernel(const float* __restrict__ emb, float* __restrict__ inv_norm,
                                    _Float16* __restrict__ eh, _Float16* __restrict__ el) {
    int row  = blockIdx.x * 4 + (threadIdx.x >> 6);
    int lane = threadIdx.x & 63;
    float4 v = reinterpret_cast<const float4*>(emb + (size_t)row * DDIM)[lane];
    float s = v.x * v.x + v.y * v.y + v.z * v.z + v.w * v.w;
    #pragma unroll
    for (int m = 32; m; m >>= 1) s += __shfl_xor(s, m, 64);
    float inv = 1.0f / fmaxf(sqrtf(s), 1e-12f);
    if (lane == 0) inv_norm[row] = inv;   // used only by fallback path
    float sv[4] = {v.x * inv, v.y * inv, v.z * inv, v.w * inv};
    half4v h, lo;
    #pragma unroll
    for (int j = 0; j < 4; ++j) {
        _Float16 hh = (_Float16)sv[j];
        h[j]  = hh;
        lo[j] = (_Float16)((sv[j] - (float)hh) * LSCALE);
    }
    *reinterpret_cast<half4v*>(eh + (size_t)row * DDIM + lane * 4) = h;
    *reinterpret_cast<half4v*>(el + (size_t)row * DDIM + lane * 4) = lo;
}

// legacy norm-only (fallback path)
__global__ void norm_emb_kernel(const float* __restrict__ emb, float* __restrict__ inv_norm) {
    int row  = blockIdx.x * 4 + (threadIdx.x >> 6);
    int lane = threadIdx.x & 63;
    float4 v = reinterpret_cast<const float4*>(emb + (size_t)row * DDIM)[lane];
    float s = v.x * v.x + v.y * v.y + v.z * v.z + v.w * v.w;
    #pragma unroll
    for (int m = 32; m; m >>= 1) s += __shfl_xor(s, m, 64);
    if (lane == 0) inv_norm[row] = 1.0f / fmaxf(sqrtf(s), 1e-12f);
}

__global__ void split_x_kernel(const float* __restrict__ x,
                               _Float16* __restrict__ xh, _Float16* __restrict__ xl) {
    int i = (blockIdx.x * 256 + threadIdx.x) * 8;
    float4 v0 = *reinterpret_cast<const float4*>(x + i);
    float4 v1 = *reinterpret_cast<const float4*>(x + i + 4);
    float v[8] = {v0.x, v0.y, v0.z, v0.w, v1.x, v1.y, v1.z, v1.w};
    half8v h, lo;
    #pragma unroll
    for (int j = 0; j < 8; ++j) {
        _Float16 hh = (_Float16)v[j];
        h[j]  = hh;
        lo[j] = (_Float16)((v[j] - (float)hh) * LSCALE);
    }
    *reinterpret_cast<half8v*>(xh + i) = h;
    *reinterpret_cast<half8v*>(xl + i) = lo;
}

// ---------- main: 3-term f16 MFMA GEMM-argmax, A from global, B in LDS ----------
// B LDS tile per array: [128 codes][32 halves] (64B rows), 16B-slot swizzle:
//   phys_slot(code, s) = s ^ ((code>>1)&3)   (codes mod 16 — bits 1-2 only)
// gload_lds writes linearly -> per-lane pre-swizzled global source.

__global__ __launch_bounds__(512, 4)
void mfma3g_kernel(const _Float16* __restrict__ xh, const _Float16* __restrict__ xl,
                   const _Float16* __restrict__ eh, const _Float16* __restrict__ el,
                   unsigned long long* __restrict__ best) {
    __shared__ _Float16 lds[2][2][4096];   // [buf][h/l][128 codes x 32 halves] = 32KB

    const int t  = threadIdx.x;
    const int l  = t & 63;
    const int w  = t >> 6;                // 0..7
    const int wy = w >> 1;                // 0..3: 32-row group
    const int wx = w & 1;                 // 0..1: 64-code half
    const int rb = blockIdx.x * BR;
    const int cs = blockIdx.y * CPS;
    const int lr = l & 15;
    const int kg = l >> 4;

    // staging: wave w stages its 16-code chunk of Bh and Bl (1KB each)
    const int s_code  = l >> 2;                      // 0..15 within chunk
    const int s_kslot = (l & 3) ^ ((l >> 3) & 3);    // pre-swizzled logical slot

    // swizzled b-frag read offset (halves, within one array): + n*512
    const int b_off = (wx * 64 + lr) * 32 + (kg ^ ((lr >> 1) & 3)) * 8;

    // A fragment pointers (rows fixed per lane; k walks via db)
    const size_t ar0 = (size_t)(rb + wy * 32 + lr) * DDIM + kg * 8;
    const size_t ar1 = (size_t)(rb + wy * 32 + 16 + lr) * DDIM + kg * 8;
    const _Float16* pah0 = xh + ar0;
    const _Float16* pah1 = xh + ar1;
    const _Float16* pal0 = xl + ar0;
    const _Float16* pal1 = xl + ar1;

    float bestv[8];
    unsigned int bestc[8];
    #pragma unroll
    for (int i = 0; i < 8; ++i) { bestv[i] = -1e30f; bestc[i] = 0; }

    f32x4 acc[2][4];
    f32x4 acc2[2][4];

    // prologue: stage slice 0
    {
        const _Float16* gph = eh + (size_t)(cs + w * 16 + s_code) * DDIM + s_kslot * 8;
        const _Float16* gpl = el + (size_t)(cs + w * 16 + s_code) * DDIM + s_kslot * 8;
        gload16(gph, &lds[0][0][w * 512]);
        gload16(gpl, &lds[0][1][w * 512]);
    }
    __syncthreads();

    int buf = 0;
    #pragma unroll 1
    for (int st = 0; st < NSLICE; ++st) {
        const int cb = cs + (st >> 3) * BCC;
        const int db = (st & 7) * BK;

        if ((st & 7) == 0) {
            #pragma unroll
            for (int m = 0; m < 2; ++m)
                #pragma unroll
                for (int n = 0; n < 4; ++n) {
                    acc[m][n]  = (f32x4){0.f, 0.f, 0.f, 0.f};
                    acc2[m][n] = (f32x4){0.f, 0.f, 0.f, 0.f};
                }
        }

        // issue next slice's B staging into the other buffer
        if (st + 1 < NSLICE) {
            const int ncb = cs + ((st + 1) >> 3) * BCC;
            const int ndb = ((st + 1) & 7) * BK;
            const size_t so = (size_t)(ncb + w * 16 + s_code) * DDIM + ndb + s_kslot * 8;
            gload16(eh + so, &lds[buf ^ 1][0][w * 512]);
            gload16(el + so, &lds[buf ^ 1][1][w * 512]);
        }

        // A fragments straight from global (L2-resident tile)
        half8v ah0 = *reinterpret_cast<const half8v*>(pah0 + db);
        half8v ah1 = *reinterpret_cast<const half8v*>(pah1 + db);
        half8v al0 = *reinterpret_cast<const half8v*>(pal0 + db);
        half8v al1 = *reinterpret_cast<const half8v*>(pal1 + db);

        const _Float16* Lh = &lds[buf][0][0];
        const _Float16* Ll = &lds[buf][1][0];
        #pragma unroll
        for (int n = 0; n < 4; ++n) {
            half8v bh = *reinterpret_cast<const half8v*>(Lh + b_off + n * 512);
            half8v bl = *reinterpret_cast<const half8v*>(Ll + b_off + n * 512);
            acc[0][n]  = __builtin_amdgcn_mfma_f32_16x16x32_f16(ah0, bh, acc[0][n],  0, 0, 0);
            acc2[0][n] = __builtin_amdgcn_mfma_f32_16x16x32_f16(ah0, bl, acc2[0][n], 0, 0, 0);
            acc2[0][n] = __builtin_amdgcn_mfma_f32_16x16x32_f16(al0, bh, acc2[0][n], 0, 0, 0);
            acc[1][n]  = __builtin_amdgcn_mfma_f32_16x16x32_f16(ah1, bh, acc[1][n],  0, 0, 0);
            acc2[1][n] = __builtin_amdgcn_mfma_f32_16x16x32_f16(ah1, bl, acc2[1][n], 0, 0, 0);
            acc2[1][n] = __builtin_amdgcn_mfma_f32_16x16x32_f16(al1, bh, acc2[1][n], 0, 0, 0);
        }

        // fold at chunk end (register-only; overlaps in-flight staging)
        if ((st & 7) == 7) {
            #pragma unroll
            for (int m = 0; m < 2; ++m)
                #pragma unroll
                for (int r = 0; r < 4; ++r) {
                    int bi = m * 4 + r;
                    #pragma unroll
                    for (int n = 0; n < 4; ++n) {
                        float v = acc[m][n][r] + acc2[m][n][r] * INV_LSCALE;
                        unsigned int code = cb + wx * 64 + n * 16 + lr;
                        if (v > bestv[bi]) { bestv[bi] = v; bestc[bi] = code; }
                    }
                }
        }

        __syncthreads();   // drains staging vmcnt + lds reads (depth-1 protocol)
        buf ^= 1;
    }

    // reduce across the 16 code-columns (lane bits 0..3); ties -> smaller code
    #pragma unroll
    for (int mb = 1; mb < 16; mb <<= 1) {
        #pragma unroll
        for (int i = 0; i < 8; ++i) {
            float ov        = __shfl_xor(bestv[i], mb, 64);
            unsigned int oc = __shfl_xor(bestc[i], mb, 64);
            if (ov > bestv[i] || (ov == bestv[i] && oc < bestc[i])) {
                bestv[i] = ov; bestc[i] = oc;
            }
        }
    }
    if (lr == 0) {
        #pragma unroll
        for (int m = 0; m < 2; ++m)
            #pragma unroll
            for (int r = 0; r < 4; ++r) {
                int row_global = rb + wy * 32 + m * 16 + (l >> 4) * 4 + r;
                int bi = m * 4 + r;
                unsigned long long key =
                    ((unsigned long long)fkey(bestv[bi]) << 32) |
                    (unsigned long long)(0xFFFFFFFFu - bestc[bi]);
                atomicMax(&best[row_global], key);
            }
    }
}

// ---------- fallback (R4, proven): in-loop split staging ----------
#define LDP  (BK + 8)

__device__ __forceinline__ void split4(float a, float b, float c, float d,
                                       half4v& h, half4v& lo) {
    h[0] = (_Float16)a; lo[0] = (_Float16)((a - (float)h[0]) * LSCALE);
    h[1] = (_Float16)b; lo[1] = (_Float16)((b - (float)h[1]) * LSCALE);
    h[2] = (_Float16)c; lo[2] = (_Float16)((c - (float)h[2]) * LSCALE);
    h[3] = (_Float16)d; lo[3] = (_Float16)((d - (float)h[3]) * LSCALE);
}

__global__ __launch_bounds__(256, 2)
void mfma_argmax_fb(const float* __restrict__ x, const float* __restrict__ emb,
                    const float* __restrict__ invn, unsigned long long* __restrict__ best) {
    __shared__ _Float16 Ah[BR][LDP];
    __shared__ _Float16 Al[BR][LDP];
    __shared__ _Float16 Bh[BCC][LDP];
    __shared__ _Float16 Bl[BCC][LDP];
    const int t = threadIdx.x, l = t & 63, wid = t >> 6;
    const int wy = wid >> 1, wx = wid & 1;
    const int rb = blockIdx.x * BR, cs = blockIdx.y * CPS;
    const int lr = l & 15, lk = (l >> 4) * 8;
    const int srow = t >> 3, sc4 = (t & 7) * 4;
    float bestv[16]; unsigned int bestc[16];
    #pragma unroll
    for (int i = 0; i < 16; ++i) { bestv[i] = -1e30f; bestc[i] = 0; }
    #pragma unroll 1
    for (int cc = 0; cc < CPS; cc += BCC) {
        const int cb = cs + cc;
        float bn[4];
        #pragma unroll
        for (int it = 0; it < 4; ++it) bn[it] = invn[cb + srow + it * 32];
        f32x4 acc[4][4], acc2[4][4];
        #pragma unroll
        for (int m = 0; m < 4; ++m)
            #pragma unroll
            for (int n = 0; n < 4; ++n) {
                acc[m][n] = (f32x4){0.f,0.f,0.f,0.f}; acc2[m][n] = (f32x4){0.f,0.f,0.f,0.f};
            }
        #pragma unroll 1
        for (int db = 0; db < DDIM; db += BK) {
            __syncthreads();
            #pragma unroll
            for (int it = 0; it < 4; ++it) {
                int row = srow + it * 32;
                float4 av = *reinterpret_cast<const float4*>(x + (size_t)(rb + row) * DDIM + db + sc4);
                half4v h, lo;
                split4(av.x, av.y, av.z, av.w, h, lo);
                *reinterpret_cast<half4v*>(&Ah[row][sc4]) = h;
                *reinterpret_cast<half4v*>(&Al[row][sc4]) = lo;
                float4 bv = *reinterpret_cast<const float4*>(emb + (size_t)(cb + row) * DDIM + db + sc4);
                float s = bn[it];
                split4(bv.x * s, bv.y * s, bv.z * s, bv.w * s, h, lo);
                *reinterpret_cast<half4v*>(&Bh[row][sc4]) = h;
                *reinterpret_cast<half4v*>(&Bl[row][sc4]) = lo;
            }
            __syncthreads();
            half8v ah[4], al[4];
            #pragma unroll
            for (int m = 0; m < 4; ++m) {
                ah[m] = *reinterpret_cast<const half8v*>(&Ah[wy * 64 + m * 16 + lr][lk]);
                al[m] = *reinterpret_cast<const half8v*>(&Al[wy * 64 + m * 16 + lr][lk]);
            }
            #pragma unroll
            for (int n = 0; n < 4; ++n) {
                half8v bh = *reinterpret_cast<const half8v*>(&Bh[wx * 64 + n * 16 + lr][lk]);
                half8v bl = *reinterpret_cast<const half8v*>(&Bl[wx * 64 + n * 16 + lr][lk]);
                #pragma unroll
                for (int m = 0; m < 4; ++m) {
                    acc[m][n]  = __builtin_amdgcn_mfma_f32_16x16x32_f16(ah[m], bh, acc[m][n],  0, 0, 0);
                    acc2[m][n] = __builtin_amdgcn_mfma_f32_16x16x32_f16(ah[m], bl, acc2[m][n], 0, 0, 0);
                    acc2[m][n] = __builtin_amdgcn_mfma_f32_16x16x32_f16(al[m], bh, acc2[m][n], 0, 0, 0);
                }
            }
        }
        #pragma unroll
        for (int m = 0; m < 4; ++m)
            #pragma unroll
            for (int r = 0; r < 4; ++r) {
                int bi = m * 4 + r;
                #pragma unroll
                for (int n = 0; n < 4; ++n) {
                    float v = acc[m][n][r] + acc2[m][n][r] * INV_LSCALE;
                    unsigned int code = cb + wx * 64 + n * 16 + lr;
                    if (v > bestv[bi]) { bestv[bi] = v; bestc[bi] = code; }
                }
            }
    }
    #pragma unroll
    for (int mb = 1; mb < 16; mb <<= 1) {
        #pragma unroll
        for (int i = 0; i < 16; ++i) {
            float ov = __shfl_xor(bestv[i], mb, 64);
            unsigned int oc = __shfl_xor(bestc[i], mb, 64);
            if (ov > bestv[i] || (ov == bestv[i] && oc < bestc[i])) { bestv[i] = ov; bestc[i] = oc; }
        }
    }
    if (lr == 0) {
        #pragma unroll
        for (int m = 0; m < 4; ++m)
            #pragma unroll
            for (int r = 0; r < 4; ++r) {
                int row_global = rb + wy * 64 + m * 16 + (l >> 4) * 4 + r;
                int bi = m * 4 + r;
                unsigned long long key = ((unsigned long long)fkey(bestv[bi]) << 32) |
                                         (unsigned long long)(0xFFFFFFFFu - bestc[bi]);
                atomicMax(&best[row_global], key);
            }
    }
}

// gather un-normalized embedding rows + write indices as float (4 rows/block)
__global__ void finalize_kernel(const unsigned long long* __restrict__ best,
                                const float* __restrict__ emb,
                                float* __restrict__ out) {
    int row  = blockIdx.x * 4 + (threadIdx.x >> 6);
    int lane = threadIdx.x & 63;
    unsigned long long b = best[row];
    unsigned int code = 0xFFFFFFFFu - (unsigned int)(b & 0xFFFFFFFFull);
    float4 v = reinterpret_cast<const float4*>(emb + (size_t)code * DDIM)[lane];
    reinterpret_cast<float4*>(out + (size_t)row * DDIM)[lane] = v;
    if (lane == 0) out[(size_t)M_ROWS * DDIM + row] = (float)code;
}

extern "C" void kernel_launch(void* const* d_in, const int* in_sizes, int n_in,
                              void* d_out, int out_size, void* d_ws, size_t ws_size,
                              hipStream_t stream) {
    const float* x   = (const float*)d_in[0];
    const float* emb = (const float*)d_in[1];
    float* out = (float*)d_out;

    // ws: [best u64 x 16384 = 128KB][inv_norm 32KB][xh 8MB][xl 8MB][eh 4MB][el 4MB]
    unsigned long long* best = (unsigned long long*)d_ws;
    float* inv_norm = (float*)((char*)d_ws + 128 * 1024);
    const size_t split_off = 160 * 1024;
    const size_t need = split_off +
                        (size_t)M_ROWS * DDIM * 2 * sizeof(_Float16) +
                        (size_t)KCODES * DDIM * 2 * sizeof(_Float16);

    hipMemsetAsync(best, 0, M_ROWS * sizeof(unsigned long long), stream);

    if (ws_size >= need) {
        _Float16* xh = (_Float16*)((char*)d_ws + split_off);
        _Float16* xl = xh + (size_t)M_ROWS * DDIM;
        _Float16* eh = xl + (size_t)M_ROWS * DDIM;
        _Float16* el = eh + (size_t)KCODES * DDIM;
        norm_split_e_kernel<<<KCODES / 4, 256, 0, stream>>>(emb, inv_norm, eh, el);
        split_x_kernel<<<M_ROWS * DDIM / (256 * 8), 256, 0, stream>>>(x, xh, xl);
        mfma3g_kernel<<<dim3(M_ROWS / BR, NSPLIT), 512, 0, stream>>>(xh, xl, eh, el, best);
    } else {
        norm_emb_kernel<<<KCODES / 4, 256, 0, stream>>>(emb, inv_norm);
        mfma_argmax_fb<<<dim3(M_ROWS / BR, NSPLIT), 256, 0, stream>>>(x, emb, inv_norm, best);
    }
    finalize_kernel<<<M_ROWS / 4, 256, 0, stream>>>(best, emb, out);
}

// Round 8
// 285.257 us; speedup vs baseline: 1.2716x; 1.2716x over previous
//
#include <hip/hip_runtime.h>
#include <stdint.h>

// CosineSimilarityCodebook: X[16384,256] f32, EMB[8192,256] f32 (re-l2norm'd).
// out = [quantized 16384*256 f32][indices 16384 as f32]
// R8: R5's proven LDS-staged 3-term split-f16 MFMA body (212us, absmax 0)
// + T4 counted-vmcnt two-barrier pipeline (loads stay in flight across the
// barrier, no vmcnt(0) drain in steady state) + T5 setprio around MFMA.
// R6's A-from-global experiment REVERTED (27% MfmaUtil: load->MFMA dep chain).
// Math identical to R4/R5/R7 (absmax 0.0 x3): dist = hh + (h*lo' + lo'*h)/512.

#define M_ROWS 16384
#define KCODES 8192
#define DDIM   256

#define BR   128
#define BCC  128
#define BK   32
#define NSPLIT 8
#define CPS  (KCODES / NSPLIT)              // 1024
#define NSLICE ((CPS / BCC) * (DDIM / BK))  // 64
#define LSCALE     512.0f
#define INV_LSCALE (1.0f / 512.0f)
#define TILE_H 4096                          // halves per tile: 128 rows * 32

typedef _Float16 half4v __attribute__((ext_vector_type(4)));
typedef _Float16 half8v __attribute__((ext_vector_type(8)));
typedef float    f32x4  __attribute__((ext_vector_type(4)));

__device__ __forceinline__ unsigned int fkey(float f) {
    unsigned int u = __float_as_uint(f);
    return (u & 0x80000000u) ? ~u : (u | 0x80000000u);
}

__device__ __forceinline__ void gload16(const void* g, void* l) {
    __builtin_amdgcn_global_load_lds(
        (const __attribute__((address_space(1))) void*)g,
        (__attribute__((address_space(3))) void*)l, 16, 0, 0);
}

// ---------- precompute ----------

// fused: per-row l2 norm + scale + f16 hi/lo split for embeddings (wave per row)
__global__ void norm_split_e_kernel(const float* __restrict__ emb, float* __restrict__ inv_norm,
                                    _Float16* __restrict__ eh, _Float16* __restrict__ el) {
    int row  = blockIdx.x * 4 + (threadIdx.x >> 6);
    int lane = threadIdx.x & 63;
    float4 v = reinterpret_cast<const float4*>(emb + (size_t)row * DDIM)[lane];
    float s = v.x * v.x + v.y * v.y + v.z * v.z + v.w * v.w;
    #pragma unroll
    for (int m = 32; m; m >>= 1) s += __shfl_xor(s, m, 64);
    float inv = 1.0f / fmaxf(sqrtf(s), 1e-12f);
    if (lane == 0) inv_norm[row] = inv;   // used only by fallback path
    float sv[4] = {v.x * inv, v.y * inv, v.z * inv, v.w * inv};
    half4v h, lo;
    #pragma unroll
    for (int j = 0; j < 4; ++j) {
        _Float16 hh = (_Float16)sv[j];
        h[j]  = hh;
        lo[j] = (_Float16)((sv[j] - (float)hh) * LSCALE);
    }
    *reinterpret_cast<half4v*>(eh + (size_t)row * DDIM + lane * 4) = h;
    *reinterpret_cast<half4v*>(el + (size_t)row * DDIM + lane * 4) = lo;
}

// legacy norm-only (fallback path)
__global__ void norm_emb_kernel(const float* __restrict__ emb, float* __restrict__ inv_norm) {
    int row  = blockIdx.x * 4 + (threadIdx.x >> 6);
    int lane = threadIdx.x & 63;
    float4 v = reinterpret_cast<const float4*>(emb + (size_t)row * DDIM)[lane];
    float s = v.x * v.x + v.y * v.y + v.z * v.z + v.w * v.w;
    #pragma unroll
    for (int m = 32; m; m >>= 1) s += __shfl_xor(s, m, 64);
    if (lane == 0) inv_norm[row] = 1.0f / fmaxf(sqrtf(s), 1e-12f);
}

__global__ void split_x_kernel(const float* __restrict__ x,
                               _Float16* __restrict__ xh, _Float16* __restrict__ xl) {
    int i = (blockIdx.x * 256 + threadIdx.x) * 8;
    float4 v0 = *reinterpret_cast<const float4*>(x + i);
    float4 v1 = *reinterpret_cast<const float4*>(x + i + 4);
    float v[8] = {v0.x, v0.y, v0.z, v0.w, v1.x, v1.y, v1.z, v1.w};
    half8v h, lo;
    #pragma unroll
    for (int j = 0; j < 8; ++j) {
        _Float16 hh = (_Float16)v[j];
        h[j]  = hh;
        lo[j] = (_Float16)((v[j] - (float)hh) * LSCALE);
    }
    *reinterpret_cast<half8v*>(xh + i) = h;
    *reinterpret_cast<half8v*>(xl + i) = lo;
}

// ---------- main: 3-term f16 MFMA GEMM-argmax (R5 body, T4 pipeline) ----------
// LDS tile [128 rows][32 halves] (64B rows), 16B-slot swizzle:
//   byte(row, kg) = row*64 + (kg ^ ((row>>1)&3))*16
// gload_lds writes linearly -> global source pre-swizzled per-lane.
// Pipeline per slice (each wave issues exactly 8 gloads/slice):
//   issue(st+1 -> buf^1); s_waitcnt vmcnt(8)   // st's loads landed, 8 in flight
//   s_barrier                                   // buf valid for all waves
//   ds_read + MFMA(buf) [setprio 1]
//   s_barrier                                   // all reads of buf done -> next
//   flip                                        //  iter may overwrite buf

__global__ __launch_bounds__(256, 2)
void mfma3p_kernel(const _Float16* __restrict__ xh, const _Float16* __restrict__ xl,
                   const _Float16* __restrict__ eh, const _Float16* __restrict__ el,
                   unsigned long long* __restrict__ best) {
    __shared__ _Float16 lds[2][4 * TILE_H];   // 2 bufs * 4 tiles * 8KB = 64KB

    const int t  = threadIdx.x;
    const int l  = t & 63;
    const int w  = t >> 6;                 // wave id; wave w stages tile w
    const int wy = w >> 1, wx = w & 1;     // 2x2 wave grid, 64x64 each
    const int rb = blockIdx.x * BR;
    const int cs = blockIdx.y * CPS;
    const int lr = l & 15;
    const int kg = l >> 4;

    // staging lane decomposition (within a 1KB chunk = 16 rows x 4 slots)
    const int s_row = l >> 2;
    const int s_kg  = (l & 3) ^ ((l >> 3) & 3);

    // ds_read swizzled per-lane offset (halves): row*32 + slot*8
    const int rd_off = lr * 32 + (kg ^ ((lr >> 1) & 3)) * 8;
    const int a_base = wy * 64 * 32 + rd_off;     // + m*16*32
    const int b_base = wx * 64 * 32 + rd_off;     // + n*16*32

    const _Float16* gsrc = (w == 0) ? xh : (w == 1) ? xl : (w == 2) ? eh : el;
    const int g_is_x = (w < 2);

    float bestv[16];
    unsigned int bestc[16];
    #pragma unroll
    for (int i = 0; i < 16; ++i) { bestv[i] = -1e30f; bestc[i] = 0; }

    f32x4 acc[4][4];    // hi*hi
    f32x4 acc2[4][4];   // cross terms (scaled by 512)

    // prologue: issue slice 0's staging (8 gloads, stay in flight)
    {
        const _Float16* gp = gsrc + (g_is_x ? rb : cs) * DDIM + s_row * DDIM + s_kg * 8;
        _Float16* lp = &lds[0][w * TILE_H];
        #pragma unroll
        for (int c = 0; c < 8; ++c)
            gload16(gp + c * 16 * DDIM, lp + c * 512);
    }

    int buf = 0;
    #pragma unroll 1
    for (int st = 0; st < NSLICE; ++st) {
        const int cb = cs + (st >> 3) * BCC;

        if ((st & 7) == 0) {
            #pragma unroll
            for (int m = 0; m < 4; ++m)
                #pragma unroll
                for (int n = 0; n < 4; ++n) {
                    acc[m][n]  = (f32x4){0.f, 0.f, 0.f, 0.f};
                    acc2[m][n] = (f32x4){0.f, 0.f, 0.f, 0.f};
                }
        }

        // issue next slice's staging; wait only for CURRENT slice's loads
        if (st + 1 < NSLICE) {
            const int ncb = cs + ((st + 1) >> 3) * BCC;
            const int ndb = ((st + 1) & 7) * BK;
            const _Float16* gp = gsrc + (g_is_x ? rb : ncb) * DDIM + ndb
                                 + s_row * DDIM + s_kg * 8;
            _Float16* lp = &lds[buf ^ 1][w * TILE_H];
            #pragma unroll
            for (int c = 0; c < 8; ++c)
                gload16(gp + c * 16 * DDIM, lp + c * 512);
            asm volatile("s_waitcnt vmcnt(8)" ::: "memory");
        } else {
            asm volatile("s_waitcnt vmcnt(0)" ::: "memory");
        }
        __builtin_amdgcn_s_barrier();          // buf now valid block-wide
        __builtin_amdgcn_sched_barrier(0);

        // compute current slice
        const _Float16* L = lds[buf];
        half8v ah[4], al[4];
        #pragma unroll
        for (int m = 0; m < 4; ++m) {
            ah[m] = *reinterpret_cast<const half8v*>(&L[0 * TILE_H + a_base + m * 512]);
            al[m] = *reinterpret_cast<const half8v*>(&L[1 * TILE_H + a_base + m * 512]);
        }
        __builtin_amdgcn_s_setprio(1);
        #pragma unroll
        for (int n = 0; n < 4; ++n) {
            half8v bh = *reinterpret_cast<const half8v*>(&L[2 * TILE_H + b_base + n * 512]);
            half8v bl = *reinterpret_cast<const half8v*>(&L[3 * TILE_H + b_base + n * 512]);
            #pragma unroll
            for (int m = 0; m < 4; ++m) {
                acc[m][n]  = __builtin_amdgcn_mfma_f32_16x16x32_f16(ah[m], bh, acc[m][n],  0, 0, 0);
                acc2[m][n] = __builtin_amdgcn_mfma_f32_16x16x32_f16(ah[m], bl, acc2[m][n], 0, 0, 0);
                acc2[m][n] = __builtin_amdgcn_mfma_f32_16x16x32_f16(al[m], bh, acc2[m][n], 0, 0, 0);
            }
        }
        __builtin_amdgcn_s_setprio(0);

        // fold at chunk end (register-only)
        if ((st & 7) == 7) {
            #pragma unroll
            for (int m = 0; m < 4; ++m)
                #pragma unroll
                for (int r = 0; r < 4; ++r) {
                    int bi = m * 4 + r;
                    #pragma unroll
                    for (int n = 0; n < 4; ++n) {
                        float v = acc[m][n][r] + acc2[m][n][r] * INV_LSCALE;
                        unsigned int code = cb + wx * 64 + n * 16 + lr;
                        if (v > bestv[bi]) { bestv[bi] = v; bestc[bi] = code; }
                    }
                }
        }

        __builtin_amdgcn_sched_barrier(0);
        __builtin_amdgcn_s_barrier();          // reads of buf done block-wide
        buf ^= 1;
    }

    // reduce across the 16 code-columns (lane bits 0..3); ties -> smaller code
    #pragma unroll
    for (int mb = 1; mb < 16; mb <<= 1) {
        #pragma unroll
        for (int i = 0; i < 16; ++i) {
            float ov        = __shfl_xor(bestv[i], mb, 64);
            unsigned int oc = __shfl_xor(bestc[i], mb, 64);
            if (ov > bestv[i] || (ov == bestv[i] && oc < bestc[i])) {
                bestv[i] = ov; bestc[i] = oc;
            }
        }
    }
    if (lr == 0) {
        #pragma unroll
        for (int m = 0; m < 4; ++m)
            #pragma unroll
            for (int r = 0; r < 4; ++r) {
                int row_global = rb + wy * 64 + m * 16 + (l >> 4) * 4 + r;
                int bi = m * 4 + r;
                unsigned long long key =
                    ((unsigned long long)fkey(bestv[bi]) << 32) |
                    (unsigned long long)(0xFFFFFFFFu - bestc[bi]);
                atomicMax(&best[row_global], key);
            }
    }
}

// ---------- fallback (R4, proven): in-loop split staging ----------
#define LDP  (BK + 8)

__device__ __forceinline__ void split4(float a, float b, float c, float d,
                                       half4v& h, half4v& lo) {
    h[0] = (_Float16)a; lo[0] = (_Float16)((a - (float)h[0]) * LSCALE);
    h[1] = (_Float16)b; lo[1] = (_Float16)((b - (float)h[1]) * LSCALE);
    h[2] = (_Float16)c; lo[2] = (_Float16)((c - (float)h[2]) * LSCALE);
    h[3] = (_Float16)d; lo[3] = (_Float16)((d - (float)h[3]) * LSCALE);
}

__global__ __launch_bounds__(256, 2)
void mfma_argmax_fb(const float* __restrict__ x, const float* __restrict__ emb,
                    const float* __restrict__ invn, unsigned long long* __restrict__ best) {
    __shared__ _Float16 Ah[BR][LDP];
    __shared__ _Float16 Al[BR][LDP];
    __shared__ _Float16 Bh[BCC][LDP];
    __shared__ _Float16 Bl[BCC][LDP];
    const int t = threadIdx.x, l = t & 63, wid = t >> 6;
    const int wy = wid >> 1, wx = wid & 1;
    const int rb = blockIdx.x * BR, cs = blockIdx.y * CPS;
    const int lr = l & 15, lk = (l >> 4) * 8;
    const int srow = t >> 3, sc4 = (t & 7) * 4;
    float bestv[16]; unsigned int bestc[16];
    #pragma unroll
    for (int i = 0; i < 16; ++i) { bestv[i] = -1e30f; bestc[i] = 0; }
    #pragma unroll 1
    for (int cc = 0; cc < CPS; cc += BCC) {
        const int cb = cs + cc;
        float bn[4];
        #pragma unroll
        for (int it = 0; it < 4; ++it) bn[it] = invn[cb + srow + it * 32];
        f32x4 acc[4][4], acc2[4][4];
        #pragma unroll
        for (int m = 0; m < 4; ++m)
            #pragma unroll
            for (int n = 0; n < 4; ++n) {
                acc[m][n] = (f32x4){0.f,0.f,0.f,0.f}; acc2[m][n] = (f32x4){0.f,0.f,0.f,0.f};
            }
        #pragma unroll 1
        for (int db = 0; db < DDIM; db += BK) {
            __syncthreads();
            #pragma unroll
            for (int it = 0; it < 4; ++it) {
                int row = srow + it * 32;
                float4 av = *reinterpret_cast<const float4*>(x + (size_t)(rb + row) * DDIM + db + sc4);
                half4v h, lo;
                split4(av.x, av.y, av.z, av.w, h, lo);
                *reinterpret_cast<half4v*>(&Ah[row][sc4]) = h;
                *reinterpret_cast<half4v*>(&Al[row][sc4]) = lo;
                float4 bv = *reinterpret_cast<const float4*>(emb + (size_t)(cb + row) * DDIM + db + sc4);
                float s = bn[it];
                split4(bv.x * s, bv.y * s, bv.z * s, bv.w * s, h, lo);
                *reinterpret_cast<half4v*>(&Bh[row][sc4]) = h;
                *reinterpret_cast<half4v*>(&Bl[row][sc4]) = lo;
            }
            __syncthreads();
            half8v ah[4], al[4];
            #pragma unroll
            for (int m = 0; m < 4; ++m) {
                ah[m] = *reinterpret_cast<const half8v*>(&Ah[wy * 64 + m * 16 + lr][lk]);
                al[m] = *reinterpret_cast<const half8v*>(&Al[wy * 64 + m * 16 + lr][lk]);
            }
            #pragma unroll
            for (int n = 0; n < 4; ++n) {
                half8v bh = *reinterpret_cast<const half8v*>(&Bh[wx * 64 + n * 16 + lr][lk]);
                half8v bl = *reinterpret_cast<const half8v*>(&Bl[wx * 64 + n * 16 + lr][lk]);
                #pragma unroll
                for (int m = 0; m < 4; ++m) {
                    acc[m][n]  = __builtin_amdgcn_mfma_f32_16x16x32_f16(ah[m], bh, acc[m][n],  0, 0, 0);
                    acc2[m][n] = __builtin_amdgcn_mfma_f32_16x16x32_f16(ah[m], bl, acc2[m][n], 0, 0, 0);
                    acc2[m][n] = __builtin_amdgcn_mfma_f32_16x16x32_f16(al[m], bh, acc2[m][n], 0, 0, 0);
                }
            }
        }
        #pragma unroll
        for (int m = 0; m < 4; ++m)
            #pragma unroll
            for (int r = 0; r < 4; ++r) {
                int bi = m * 4 + r;
                #pragma unroll
                for (int n = 0; n < 4; ++n) {
                    float v = acc[m][n][r] + acc2[m][n][r] * INV_LSCALE;
                    unsigned int code = cb + wx * 64 + n * 16 + lr;
                    if (v > bestv[bi]) { bestv[bi] = v; bestc[bi] = code; }
                }
            }
    }
    #pragma unroll
    for (int mb = 1; mb < 16; mb <<= 1) {
        #pragma unroll
        for (int i = 0; i < 16; ++i) {
            float ov = __shfl_xor(bestv[i], mb, 64);
            unsigned int oc = __shfl_xor(bestc[i], mb, 64);
            if (ov > bestv[i] || (ov == bestv[i] && oc < bestc[i])) { bestv[i] = ov; bestc[i] = oc; }
        }
    }
    if (lr == 0) {
        #pragma unroll
        for (int m = 0; m < 4; ++m)
            #pragma unroll
            for (int r = 0; r < 4; ++r) {
                int row_global = rb + wy * 64 + m * 16 + (l >> 4) * 4 + r;
                int bi = m * 4 + r;
                unsigned long long key = ((unsigned long long)fkey(bestv[bi]) << 32) |
                                         (unsigned long long)(0xFFFFFFFFu - bestc[bi]);
                atomicMax(&best[row_global], key);
            }
    }
}

// gather un-normalized embedding rows + write indices as float (4 rows/block)
__global__ void finalize_kernel(const unsigned long long* __restrict__ best,
                                const float* __restrict__ emb,
                                float* __restrict__ out) {
    int row  = blockIdx.x * 4 + (threadIdx.x >> 6);
    int lane = threadIdx.x & 63;
    unsigned long long b = best[row];
    unsigned int code = 0xFFFFFFFFu - (unsigned int)(b & 0xFFFFFFFFull);
    float4 v = reinterpret_cast<const float4*>(emb + (size_t)code * DDIM)[lane];
    reinterpret_cast<float4*>(out + (size_t)row * DDIM)[lane] = v;
    if (lane == 0) out[(size_t)M_ROWS * DDIM + row] = (float)code;
}

extern "C" void kernel_launch(void* const* d_in, const int* in_sizes, int n_in,
                              void* d_out, int out_size, void* d_ws, size_t ws_size,
                              hipStream_t stream) {
    const float* x   = (const float*)d_in[0];
    const float* emb = (const float*)d_in[1];
    float* out = (float*)d_out;

    // ws: [best u64 x 16384 = 128KB][inv_norm 32KB][xh 8MB][xl 8MB][eh 4MB][el 4MB]
    unsigned long long* best = (unsigned long long*)d_ws;
    float* inv_norm = (float*)((char*)d_ws + 128 * 1024);
    const size_t split_off = 160 * 1024;
    const size_t need = split_off +
                        (size_t)M_ROWS * DDIM * 2 * sizeof(_Float16) +
                        (size_t)KCODES * DDIM * 2 * sizeof(_Float16);

    hipMemsetAsync(best, 0, M_ROWS * sizeof(unsigned long long), stream);

    if (ws_size >= need) {
        _Float16* xh = (_Float16*)((char*)d_ws + split_off);
        _Float16* xl = xh + (size_t)M_ROWS * DDIM;
        _Float16* eh = xl + (size_t)M_ROWS * DDIM;
        _Float16* el = eh + (size_t)KCODES * DDIM;
        norm_split_e_kernel<<<KCODES / 4, 256, 0, stream>>>(emb, inv_norm, eh, el);
        split_x_kernel<<<M_ROWS * DDIM / (256 * 8), 256, 0, stream>>>(x, xh, xl);
        mfma3p_kernel<<<dim3(M_ROWS / BR, NSPLIT), 256, 0, stream>>>(xh, xl, eh, el, best);
    } else {
        norm_emb_kernel<<<KCODES / 4, 256, 0, stream>>>(emb, inv_norm);
        mfma_argmax_fb<<<dim3(M_ROWS / BR, NSPLIT), 256, 0, stream>>>(x, emb, inv_norm, best);
    }
    finalize_kernel<<<M_ROWS / 4, 256, 0, stream>>>(best, emb, out);
}